// Round 8
// baseline (397.822 us; speedup 1.0000x reference)
//
#include <hip/hip_runtime.h>
#include <hip/hip_bf16.h>

// B=2,S=2048 -> T=4096 tokens, D=1024, H=2048, E=8, top_k=2
#define TOK 4096
#define DD 1024
#define HH 2048
#define NE 8
#define RTOT (TOK * 2)
#define NWL 96   // worklist capacity (max live M-tiles = 64+7=71 @ BM=128)

typedef __attribute__((ext_vector_type(8))) short bf16x8;
typedef __attribute__((ext_vector_type(4))) float f32x4;

static __device__ __forceinline__ unsigned short f2bf(float f) {
  union { float f; unsigned int u; } v; v.f = f;
  unsigned int r = v.u + 0x7fffu + ((v.u >> 16) & 1u);
  return (unsigned short)(r >> 16);
}

// async global->LDS, 16B/lane; LDS dest = wave-uniform base + lane*16
static __device__ __forceinline__ void gload16(const unsigned short* g, unsigned short* l) {
  __builtin_amdgcn_global_load_lds(
      (const __attribute__((address_space(1))) unsigned int*)g,
      (__attribute__((address_space(3))) unsigned int*)l, 16, 0, 0);
}

// packed f32x2 -> bf16x2 (RNE), single HW instruction
#define CVT(d, lo, hi) asm("v_cvt_pk_bf16_f32 %0, %1, %2" : "=v"(d) : "v"(lo), "v"(hi))

// ---------------- router: fp32 scores, top-2 softmax; also emits Xb (bf16 x) ----------------
__global__ void router_k(const float* __restrict__ x, const float* __restrict__ gw,
                         unsigned short* __restrict__ xb,
                         int* __restrict__ topi, float* __restrict__ topp,
                         int* __restrict__ counts) {
  const int lane = threadIdx.x & 63;
  const int t = blockIdx.x * 4 + (threadIdx.x >> 6);
  const float4* xr = (const float4*)(x + (size_t)t * DD);
  unsigned int* xw = (unsigned int*)(xb + (size_t)t * DD);
  float acc[NE];
#pragma unroll
  for (int e = 0; e < NE; ++e) acc[e] = 0.f;
#pragma unroll
  for (int i = 0; i < 4; ++i) {
    const float4 xv = xr[i * 64 + lane];
    unsigned int p0, p1;
    CVT(p0, xv.x, xv.y);
    CVT(p1, xv.z, xv.w);
    xw[(i * 64 + lane) * 2] = p0;
    xw[(i * 64 + lane) * 2 + 1] = p1;
#pragma unroll
    for (int e = 0; e < NE; ++e) {
      const float4 gv = ((const float4*)(gw + (size_t)e * DD))[i * 64 + lane];
      acc[e] += xv.x * gv.x + xv.y * gv.y + xv.z * gv.z + xv.w * gv.w;
    }
  }
#pragma unroll
  for (int e = 0; e < NE; ++e)
#pragma unroll
    for (int s = 32; s > 0; s >>= 1) acc[e] += __shfl_xor(acc[e], s, 64);
  if (lane == 0) {
    int i0 = 0; float v0 = acc[0];
#pragma unroll
    for (int e = 1; e < NE; ++e) if (acc[e] > v0) { v0 = acc[e]; i0 = e; }
    int i1 = -1; float v1 = -1e30f;
#pragma unroll
    for (int e = 0; e < NE; ++e) if (e != i0 && acc[e] > v1) { v1 = acc[e]; i1 = e; }
    const float ex = __expf(v1 - v0);
    const float inv = 1.f / (1.f + ex);
    topi[t * 2] = i0; topi[t * 2 + 1] = i1;
    topp[t * 2] = inv; topp[t * 2 + 1] = ex * inv;
    atomicAdd(&counts[i0], 1); atomicAdd(&counts[i1], 1);
  }
}

// ---------------- weight transpose+convert ----------------
__global__ __launch_bounds__(256) void transpose_k(
    const float* __restrict__ w1, const float* __restrict__ w2, const float* __restrict__ w3,
    unsigned short* __restrict__ wgu, unsigned short* __restrict__ w3t) {
  const int z = blockIdx.y;
  const int mat = z >> 3, e = z & 7;
  __shared__ unsigned short t[64 * 72];
  const int tid = threadIdx.x;
  const int lane = tid & 63, wv = tid >> 6;

  if (mat < 2) {
    const float* in = (mat ? w2 : w1) + (size_t)e * DD * HH;
    const int tc = blockIdx.x & 31, tr = blockIdx.x >> 5;
    const int c0 = tc * 64, r0 = tr * 64;
#pragma unroll
    for (int p = 0; p < 4; ++p) {
      const int rb = (wv * 4 + p) * 4;
      ushort4 o;
      o.x = f2bf(in[(size_t)(r0 + rb + 0) * HH + c0 + lane]);
      o.y = f2bf(in[(size_t)(r0 + rb + 1) * HH + c0 + lane]);
      o.z = f2bf(in[(size_t)(r0 + rb + 2) * HH + c0 + lane]);
      o.w = f2bf(in[(size_t)(r0 + rb + 3) * HH + c0 + lane]);
      *(ushort4*)&t[lane * 72 + rb] = o;
    }
    __syncthreads();
#pragma unroll
    for (int q = 0; q < 2; ++q) {
      const int idx = q * 256 + tid;
      const int crow = idx >> 3, seg = idx & 7;
      const int j = c0 + crow;
      const int R = ((j >> 4) << 5) + (j & 15) + mat * 16;
      *(uint4*)&wgu[((size_t)e * 2 * HH + R) * DD + r0 + seg * 8] =
          *(const uint4*)&t[crow * 72 + seg * 8];
    }
  } else {
    const float* in = w3 + (size_t)e * HH * DD;
    const int tc = blockIdx.x & 15, tr = blockIdx.x >> 4;
    const int c0 = tc * 64, r0 = tr * 64;
#pragma unroll
    for (int p = 0; p < 4; ++p) {
      const int rb = (wv * 4 + p) * 4;
      ushort4 o;
      o.x = f2bf(in[(size_t)(r0 + rb + 0) * DD + c0 + lane]);
      o.y = f2bf(in[(size_t)(r0 + rb + 1) * DD + c0 + lane]);
      o.z = f2bf(in[(size_t)(r0 + rb + 2) * DD + c0 + lane]);
      o.w = f2bf(in[(size_t)(r0 + rb + 3) * DD + c0 + lane]);
      *(ushort4*)&t[lane * 72 + rb] = o;
    }
    __syncthreads();
#pragma unroll
    for (int q = 0; q < 2; ++q) {
      const int idx = q * 256 + tid;
      const int crow = idx >> 3, seg = idx & 7;
      *(uint4*)&w3t[((size_t)e * DD + c0 + crow) * HH + r0 + seg * 8] =
          *(const uint4*)&t[crow * 72 + seg * 8];
    }
  }
}

// ---------------- scan: offsets/cursor + M-tile worklist (BM=128) ----------------
__global__ void scan_k(const int* __restrict__ counts, int* __restrict__ offsets,
                       int* __restrict__ cursor, int* __restrict__ wl) {
  if (threadIdx.x == 0) {
    int s = 0, nt = 0;
    for (int e = 0; e < NE; ++e) {
      offsets[e] = s; cursor[e] = s;
      for (int m0 = 0; m0 < counts[e]; m0 += 128) wl[nt++] = (e << 20) | m0;
      s += counts[e];
    }
    for (int i = nt; i < NWL; ++i) wl[i] = -1;
  }
}

__global__ void scatter_k(const int* __restrict__ topi, const float* __restrict__ topp,
                          int* __restrict__ cursor, int* __restrict__ perm,
                          float* __restrict__ prow) {
  const int t = blockIdx.x * 256 + threadIdx.x;
#pragma unroll
  for (int k = 0; k < 2; ++k) {
    const int e = topi[t * 2 + k];
    const int pos = atomicAdd(&cursor[e], 1);
    perm[pos] = t;
    prow[pos] = topp[t * 2 + k];
  }
}

// ---------------- GEMM1: X(gathered bf16) @ wgu(bf16) -> h = silu(g)*u ----------------
// BM=128, BN=128 wgu-rows (64 h-cols), BK=64; 4 waves (2x2), single-buffer 32KB LDS.
// 1D grid, 256-block bands: bx = bid&31 (B-panel), wl-slot = band*8 + (bid>>5)&7.
// Same-B blocks at bid stride 32 -> same bid%8 -> same XCD (round-robin) -> B L2-resident.
__global__ __launch_bounds__(256) void gemm1_k(
    const unsigned short* __restrict__ Xb, const unsigned short* __restrict__ wgu,
    const int* __restrict__ counts, const int* __restrict__ offsets,
    const int* __restrict__ perm, const int* __restrict__ wl,
    unsigned short* __restrict__ hbuf) {
  const int bid = blockIdx.x;
  const int band = bid >> 8, r_ = bid & 255;
  const int bx = r_ & 31;
  const int enc = wl[band * 8 + (r_ >> 5)];
  if (enc < 0) return;
  const int e = enc >> 20, m0 = enc & 0xFFFFF;
  const int ne = counts[e], off = offsets[e];

  __shared__ unsigned short As[128 * 64];
  __shared__ unsigned short Bs[128 * 64];

  const int tid = threadIdx.x, lane = tid & 63, wv = tid >> 6;
  const int srow = lane >> 3;
  const int schunk = ((lane & 7) ^ srow) * 8;

  const unsigned short* pA[4];
  const unsigned short* pB[4];
#pragma unroll
  for (int q = 0; q < 4; ++q) {
    const int row = wv * 32 + q * 8 + srow;
    pA[q] = Xb + (size_t)perm[off + min(m0 + row, ne - 1)] * DD + schunk;
    pB[q] = wgu + ((size_t)e * 2 * HH + bx * 128 + row) * DD + schunk;
  }

  const int wr = wv >> 1, wc = wv & 1;
  const int lr = lane & 15, kc = lane >> 4;

  f32x4 acc[4][4];
#pragma unroll
  for (int a = 0; a < 4; ++a)
#pragma unroll
    for (int b = 0; b < 4; ++b) acc[a][b] = f32x4{0.f, 0.f, 0.f, 0.f};

  for (int t = 0; t < DD / 64; ++t) {
#pragma unroll
    for (int q = 0; q < 4; ++q) {
      gload16(pA[q], &As[(wv * 32 + q * 8) * 64]); pA[q] += 64;
      gload16(pB[q], &Bs[(wv * 32 + q * 8) * 64]); pB[q] += 64;
    }
    __syncthreads();
#pragma unroll
    for (int kk = 0; kk < 2; ++kk) {
      bf16x8 af[4], bf[4];
#pragma unroll
      for (int mf = 0; mf < 4; ++mf)
        af[mf] = *(const bf16x8*)&As[(wr * 64 + mf * 16 + lr) * 64 + ((kk * 4 + kc) ^ (lr & 7)) * 8];
#pragma unroll
      for (int nf = 0; nf < 4; ++nf)
        bf[nf] = *(const bf16x8*)&Bs[(wc * 64 + nf * 16 + lr) * 64 + ((kk * 4 + kc) ^ (lr & 7)) * 8];
#pragma unroll
      for (int mf = 0; mf < 4; ++mf)
#pragma unroll
        for (int nf = 0; nf < 4; ++nf)
          acc[mf][nf] = __builtin_amdgcn_mfma_f32_16x16x32_bf16(af[mf], bf[nf], acc[mf][nf], 0, 0, 0);
    }
    __syncthreads();
  }

  // epilogue: nf even = G, nf odd = U (same 16 h-cols)
#pragma unroll
  for (int mf = 0; mf < 4; ++mf)
#pragma unroll
    for (int np = 0; np < 2; ++np) {
      const f32x4 g = acc[mf][2 * np], u = acc[mf][2 * np + 1];
      const int hcol = bx * 64 + (wc * 2 + np) * 16 + lr;
#pragma unroll
      for (int r = 0; r < 4; ++r) {
        const int rl = m0 + wr * 64 + mf * 16 + kc * 4 + r;
        if (rl < ne) {
          const float gg = g[r], uu = u[r];
          const float hv = gg / (1.f + __expf(-gg)) * uu;
          hbuf[(size_t)(off + rl) * HH + hcol] = f2bf(hv);
        }
      }
    }
}

// ---------------- GEMM2: h(bf16) @ w3t(bf16) * prob -> atomicAdd into out ----------------
// BM=128, BN=128, BK=64; 4 waves (2x2), single-buffer LDS, K=2048.
// bands of 256: bx = bid&7 (B-panel), wl-slot = band*32 + (bid>>3)&31.
__global__ __launch_bounds__(256) void gemm2_k(
    const unsigned short* __restrict__ hbuf, const unsigned short* __restrict__ w3t,
    const int* __restrict__ counts, const int* __restrict__ offsets,
    const int* __restrict__ perm, const float* __restrict__ prow,
    const int* __restrict__ wl, float* __restrict__ out) {
  const int bid = blockIdx.x;
  const int band = bid >> 8, r_ = bid & 255;
  const int bx = r_ & 7;
  const int enc = wl[band * 32 + (r_ >> 3)];
  if (enc < 0) return;
  const int e = enc >> 20, m0 = enc & 0xFFFFF;
  const int ne = counts[e], off = offsets[e];
  const int n1 = bx * 128;

  __shared__ unsigned short As[128 * 64];
  __shared__ unsigned short Bs[128 * 64];

  const int tid = threadIdx.x, lane = tid & 63, wv = tid >> 6;
  const int srow = lane >> 3;
  const int schunk = ((lane & 7) ^ srow) * 8;

  const unsigned short* pA[4];
  const unsigned short* pB[4];
#pragma unroll
  for (int q = 0; q < 4; ++q) {
    const int row = wv * 32 + q * 8 + srow;
    pA[q] = hbuf + (size_t)(off + min(m0 + row, ne - 1)) * HH + schunk;
    pB[q] = w3t + ((size_t)e * DD + n1 + row) * HH + schunk;
  }

  const int wr = wv >> 1, wc = wv & 1;
  const int lr = lane & 15, kc = lane >> 4;

  f32x4 acc[4][4];
#pragma unroll
  for (int a = 0; a < 4; ++a)
#pragma unroll
    for (int b = 0; b < 4; ++b) acc[a][b] = f32x4{0.f, 0.f, 0.f, 0.f};

  for (int t = 0; t < HH / 64; ++t) {
#pragma unroll
    for (int q = 0; q < 4; ++q) {
      gload16(pA[q], &As[(wv * 32 + q * 8) * 64]); pA[q] += 64;
      gload16(pB[q], &Bs[(wv * 32 + q * 8) * 64]); pB[q] += 64;
    }
    __syncthreads();
#pragma unroll
    for (int kk = 0; kk < 2; ++kk) {
      bf16x8 af[4], bf[4];
#pragma unroll
      for (int mf = 0; mf < 4; ++mf)
        af[mf] = *(const bf16x8*)&As[(wr * 64 + mf * 16 + lr) * 64 + ((kk * 4 + kc) ^ (lr & 7)) * 8];
#pragma unroll
      for (int nf = 0; nf < 4; ++nf)
        bf[nf] = *(const bf16x8*)&Bs[(wc * 64 + nf * 16 + lr) * 64 + ((kk * 4 + kc) ^ (lr & 7)) * 8];
#pragma unroll
      for (int mf = 0; mf < 4; ++mf)
#pragma unroll
        for (int nf = 0; nf < 4; ++nf)
          acc[mf][nf] = __builtin_amdgcn_mfma_f32_16x16x32_bf16(af[mf], bf[nf], acc[mf][nf], 0, 0, 0);
    }
    __syncthreads();
  }

  // epilogue: out[tok] += prob * acc  (fp32 atomic add, commutative -> deterministic)
#pragma unroll
  for (int mf = 0; mf < 4; ++mf)
#pragma unroll
    for (int r = 0; r < 4; ++r) {
      const int rl = m0 + wr * 64 + mf * 16 + kc * 4 + r;
      if (rl < ne) {
        const int tok = perm[off + rl];
        const float p = prow[off + rl];
        float* op = out + (size_t)tok * DD + n1 + wc * 64 + lr;
#pragma unroll
        for (int nf = 0; nf < 4; ++nf)
          atomicAdd(op + nf * 16, p * acc[mf][nf][r]);
      }
    }
}

// ---------------- workspace layout ----------------
#define WS_COUNTS 0
#define WS_OFFS 32
#define WS_CURS 64
#define WS_WL 128
#define WS_TOPI (WS_WL + NWL * 4)
#define WS_TOPP (WS_TOPI + TOK * 2 * 4)
#define WS_PERM (WS_TOPP + TOK * 2 * 4)
#define WS_PROW (WS_PERM + RTOT * 4)
#define WS_XB ((WS_PROW + RTOT * 4 + 255) & ~(size_t)255)
#define WS_H (WS_XB + (size_t)TOK * DD * 2)
#define WS_WGU (WS_H + (size_t)RTOT * HH * 2)
#define WS_W3T (WS_WGU + (size_t)NE * 2 * HH * DD * 2)
// end = WS_W3T + NE*DD*HH*2 ~= 136 MB

extern "C" void kernel_launch(void* const* d_in, const int* in_sizes, int n_in,
                              void* d_out, int out_size, void* d_ws, size_t ws_size,
                              hipStream_t stream) {
  const float* x = (const float*)d_in[0];
  const float* gw = (const float*)d_in[1];
  const float* w1 = (const float*)d_in[2];
  const float* w2 = (const float*)d_in[3];
  const float* w3 = (const float*)d_in[4];
  float* out = (float*)d_out;
  char* ws = (char*)d_ws;

  int* counts = (int*)(ws + WS_COUNTS);
  int* offsets = (int*)(ws + WS_OFFS);
  int* cursor = (int*)(ws + WS_CURS);
  int* wl = (int*)(ws + WS_WL);
  int* topi = (int*)(ws + WS_TOPI);
  float* topp = (float*)(ws + WS_TOPP);
  int* perm = (int*)(ws + WS_PERM);
  float* prow = (float*)(ws + WS_PROW);
  unsigned short* Xb = (unsigned short*)(ws + WS_XB);
  unsigned short* hbuf = (unsigned short*)(ws + WS_H);
  unsigned short* wgu = (unsigned short*)(ws + WS_WGU);
  unsigned short* w3t = (unsigned short*)(ws + WS_W3T);

  hipMemsetAsync(ws, 0, 128, stream);
  hipMemsetAsync(out, 0, (size_t)out_size * sizeof(float), stream);
  router_k<<<TOK / 4, 256, 0, stream>>>(x, gw, Xb, topi, topp, counts);
  transpose_k<<<dim3(512, 24), 256, 0, stream>>>(w1, w2, w3, wgu, w3t);
  scan_k<<<1, 64, 0, stream>>>(counts, offsets, cursor, wl);
  scatter_k<<<TOK / 256, 256, 0, stream>>>(topi, topp, cursor, perm, prow);
  // gemm1: 12 bands x 256 blocks (8 wl-slots x 32 B-panels per band); wl padded with -1
  gemm1_k<<<(NWL / 8) * 256, 256, 0, stream>>>(Xb, wgu, counts, offsets, perm, wl, hbuf);
  // gemm2: 3 bands x 256 blocks (32 wl-slots x 8 B-panels per band)
  gemm2_k<<<(NWL / 32) * 256, 256, 0, stream>>>(hbuf, w3t, counts, offsets, perm, prow, wl, out);
}

// Round 9
// 392.789 us; speedup vs baseline: 1.0128x; 1.0128x over previous
//
#include <hip/hip_runtime.h>
#include <hip/hip_bf16.h>

// B=2,S=2048 -> T=4096 tokens, D=1024, H=2048, E=8, top_k=2
#define TOK 4096
#define DD 1024
#define HH 2048
#define NE 8
#define RTOT (TOK * 2)
#define NWL 96   // worklist capacity (max live M-tiles = 64+7=71 @ BM=128)

typedef __attribute__((ext_vector_type(8))) short bf16x8;
typedef __attribute__((ext_vector_type(4))) float f32x4;

static __device__ __forceinline__ unsigned short f2bf(float f) {
  union { float f; unsigned int u; } v; v.f = f;
  unsigned int r = v.u + 0x7fffu + ((v.u >> 16) & 1u);
  return (unsigned short)(r >> 16);
}

// async global->LDS, 16B/lane; LDS dest = wave-uniform base + lane*16
static __device__ __forceinline__ void gload16(const unsigned short* g, unsigned short* l) {
  __builtin_amdgcn_global_load_lds(
      (const __attribute__((address_space(1))) unsigned int*)g,
      (__attribute__((address_space(3))) unsigned int*)l, 16, 0, 0);
}

// packed f32x2 -> bf16x2 (RNE), single HW instruction
#define CVT(d, lo, hi) asm("v_cvt_pk_bf16_f32 %0, %1, %2" : "=v"(d) : "v"(lo), "v"(hi))

#define BARX() do { asm volatile("" ::: "memory"); __builtin_amdgcn_s_barrier(); asm volatile("" ::: "memory"); } while (0)
#define VMCNT8() asm volatile("s_waitcnt vmcnt(8)" ::: "memory")
#define VMCNT0() asm volatile("s_waitcnt vmcnt(0)" ::: "memory")

// ---------------- router: fp32 scores, top-2 softmax; also emits Xb (bf16 x) ----------------
__global__ void router_k(const float* __restrict__ x, const float* __restrict__ gw,
                         unsigned short* __restrict__ xb,
                         int* __restrict__ topi, float* __restrict__ topp,
                         int* __restrict__ counts) {
  const int lane = threadIdx.x & 63;
  const int t = blockIdx.x * 4 + (threadIdx.x >> 6);
  const float4* xr = (const float4*)(x + (size_t)t * DD);
  unsigned int* xw = (unsigned int*)(xb + (size_t)t * DD);
  float acc[NE];
#pragma unroll
  for (int e = 0; e < NE; ++e) acc[e] = 0.f;
#pragma unroll
  for (int i = 0; i < 4; ++i) {
    const float4 xv = xr[i * 64 + lane];
    unsigned int p0, p1;
    CVT(p0, xv.x, xv.y);
    CVT(p1, xv.z, xv.w);
    xw[(i * 64 + lane) * 2] = p0;
    xw[(i * 64 + lane) * 2 + 1] = p1;
#pragma unroll
    for (int e = 0; e < NE; ++e) {
      const float4 gv = ((const float4*)(gw + (size_t)e * DD))[i * 64 + lane];
      acc[e] += xv.x * gv.x + xv.y * gv.y + xv.z * gv.z + xv.w * gv.w;
    }
  }
#pragma unroll
  for (int e = 0; e < NE; ++e)
#pragma unroll
    for (int s = 32; s > 0; s >>= 1) acc[e] += __shfl_xor(acc[e], s, 64);
  if (lane == 0) {
    int i0 = 0; float v0 = acc[0];
#pragma unroll
    for (int e = 1; e < NE; ++e) if (acc[e] > v0) { v0 = acc[e]; i0 = e; }
    int i1 = -1; float v1 = -1e30f;
#pragma unroll
    for (int e = 0; e < NE; ++e) if (e != i0 && acc[e] > v1) { v1 = acc[e]; i1 = e; }
    const float ex = __expf(v1 - v0);
    const float inv = 1.f / (1.f + ex);
    topi[t * 2] = i0; topi[t * 2 + 1] = i1;
    topp[t * 2] = inv; topp[t * 2 + 1] = ex * inv;
    atomicAdd(&counts[i0], 1); atomicAdd(&counts[i1], 1);
  }
}

// ---------------- weight transpose+convert ----------------
__global__ __launch_bounds__(256) void transpose_k(
    const float* __restrict__ w1, const float* __restrict__ w2, const float* __restrict__ w3,
    unsigned short* __restrict__ wgu, unsigned short* __restrict__ w3t) {
  const int z = blockIdx.y;
  const int mat = z >> 3, e = z & 7;
  __shared__ unsigned short t[64 * 72];
  const int tid = threadIdx.x;
  const int lane = tid & 63, wv = tid >> 6;

  if (mat < 2) {
    const float* in = (mat ? w2 : w1) + (size_t)e * DD * HH;
    const int tc = blockIdx.x & 31, tr = blockIdx.x >> 5;
    const int c0 = tc * 64, r0 = tr * 64;
#pragma unroll
    for (int p = 0; p < 4; ++p) {
      const int rb = (wv * 4 + p) * 4;
      ushort4 o;
      o.x = f2bf(in[(size_t)(r0 + rb + 0) * HH + c0 + lane]);
      o.y = f2bf(in[(size_t)(r0 + rb + 1) * HH + c0 + lane]);
      o.z = f2bf(in[(size_t)(r0 + rb + 2) * HH + c0 + lane]);
      o.w = f2bf(in[(size_t)(r0 + rb + 3) * HH + c0 + lane]);
      *(ushort4*)&t[lane * 72 + rb] = o;
    }
    __syncthreads();
#pragma unroll
    for (int q = 0; q < 2; ++q) {
      const int idx = q * 256 + tid;
      const int crow = idx >> 3, seg = idx & 7;
      const int j = c0 + crow;
      const int R = ((j >> 4) << 5) + (j & 15) + mat * 16;
      *(uint4*)&wgu[((size_t)e * 2 * HH + R) * DD + r0 + seg * 8] =
          *(const uint4*)&t[crow * 72 + seg * 8];
    }
  } else {
    const float* in = w3 + (size_t)e * HH * DD;
    const int tc = blockIdx.x & 15, tr = blockIdx.x >> 4;
    const int c0 = tc * 64, r0 = tr * 64;
#pragma unroll
    for (int p = 0; p < 4; ++p) {
      const int rb = (wv * 4 + p) * 4;
      ushort4 o;
      o.x = f2bf(in[(size_t)(r0 + rb + 0) * DD + c0 + lane]);
      o.y = f2bf(in[(size_t)(r0 + rb + 1) * DD + c0 + lane]);
      o.z = f2bf(in[(size_t)(r0 + rb + 2) * DD + c0 + lane]);
      o.w = f2bf(in[(size_t)(r0 + rb + 3) * DD + c0 + lane]);
      *(ushort4*)&t[lane * 72 + rb] = o;
    }
    __syncthreads();
#pragma unroll
    for (int q = 0; q < 2; ++q) {
      const int idx = q * 256 + tid;
      const int crow = idx >> 3, seg = idx & 7;
      *(uint4*)&w3t[((size_t)e * DD + c0 + crow) * HH + r0 + seg * 8] =
          *(const uint4*)&t[crow * 72 + seg * 8];
    }
  }
}

// ---------------- scan: offsets/cursor + M-tile worklist (BM=128) ----------------
__global__ void scan_k(const int* __restrict__ counts, int* __restrict__ offsets,
                       int* __restrict__ cursor, int* __restrict__ wl) {
  if (threadIdx.x == 0) {
    int s = 0, nt = 0;
    for (int e = 0; e < NE; ++e) {
      offsets[e] = s; cursor[e] = s;
      for (int m0 = 0; m0 < counts[e]; m0 += 128) wl[nt++] = (e << 20) | m0;
      s += counts[e];
    }
    for (int i = nt; i < NWL; ++i) wl[i] = -1;
  }
}

__global__ void scatter_k(const int* __restrict__ topi, const float* __restrict__ topp,
                          int* __restrict__ cursor, int* __restrict__ perm,
                          float* __restrict__ prow) {
  const int t = blockIdx.x * 256 + threadIdx.x;
#pragma unroll
  for (int k = 0; k < 2; ++k) {
    const int e = topi[t * 2 + k];
    const int pos = atomicAdd(&cursor[e], 1);
    perm[pos] = t;
    prow[pos] = topp[t * 2 + k];
  }
}

// ---------------- GEMM1: X(gathered bf16) @ wgu(bf16) -> h = silu(g)*u ----------------
// BM=128, BN=128 wgu-rows (64 h-cols), BK=64; 4 waves (2x2).
// Depth-2 dbuf, counted vmcnt(8) (T3+T4): loads stay in flight across barriers.
__global__ __launch_bounds__(256) void gemm1_k(
    const unsigned short* __restrict__ Xb, const unsigned short* __restrict__ wgu,
    const int* __restrict__ counts, const int* __restrict__ offsets,
    const int* __restrict__ perm, const int* __restrict__ wl,
    unsigned short* __restrict__ hbuf) {
  const int bid = blockIdx.x;
  const int band = bid >> 8, r_ = bid & 255;
  const int bx = r_ & 31;
  const int enc = wl[band * 8 + (r_ >> 5)];
  if (enc < 0) return;
  const int e = enc >> 20, m0 = enc & 0xFFFFF;
  const int ne = counts[e], off = offsets[e];

  __shared__ unsigned short As[2][128 * 64];
  __shared__ unsigned short Bs[2][128 * 64];

  const int tid = threadIdx.x, lane = tid & 63, wv = tid >> 6;
  const int srow = lane >> 3;
  const int schunk = ((lane & 7) ^ srow) * 8;

  const unsigned short* pA[4];
  const unsigned short* pB[4];
#pragma unroll
  for (int q = 0; q < 4; ++q) {
    const int row = wv * 32 + q * 8 + srow;
    pA[q] = Xb + (size_t)perm[off + min(m0 + row, ne - 1)] * DD + schunk;
    pB[q] = wgu + ((size_t)e * 2 * HH + bx * 128 + row) * DD + schunk;
  }

  const int wr = wv >> 1, wc = wv & 1;
  const int lr = lane & 15, kc = lane >> 4;

  f32x4 acc[4][4];
#pragma unroll
  for (int a = 0; a < 4; ++a)
#pragma unroll
    for (int b = 0; b < 4; ++b) acc[a][b] = f32x4{0.f, 0.f, 0.f, 0.f};

#define G1_ISSUE(b)                                                       \
  do {                                                                    \
    _Pragma("unroll")                                                     \
    for (int q = 0; q < 4; ++q) {                                         \
      gload16(pA[q], &As[b][(wv * 32 + q * 8) * 64]); pA[q] += 64;        \
      gload16(pB[q], &Bs[b][(wv * 32 + q * 8) * 64]); pB[q] += 64;        \
    }                                                                     \
  } while (0)

#define G1_COMPUTE(b)                                                     \
  do {                                                                    \
    _Pragma("unroll")                                                     \
    for (int kk = 0; kk < 2; ++kk) {                                      \
      bf16x8 af[4], bf[4];                                                \
      _Pragma("unroll")                                                   \
      for (int mf = 0; mf < 4; ++mf)                                      \
        af[mf] = *(const bf16x8*)&As[b][(wr * 64 + mf * 16 + lr) * 64 +   \
                                       ((kk * 4 + kc) ^ (lr & 7)) * 8];   \
      _Pragma("unroll")                                                   \
      for (int nf = 0; nf < 4; ++nf)                                      \
        bf[nf] = *(const bf16x8*)&Bs[b][(wc * 64 + nf * 16 + lr) * 64 +   \
                                       ((kk * 4 + kc) ^ (lr & 7)) * 8];   \
      _Pragma("unroll")                                                   \
      for (int mf = 0; mf < 4; ++mf)                                      \
        _Pragma("unroll")                                                 \
        for (int nf = 0; nf < 4; ++nf)                                    \
          acc[mf][nf] = __builtin_amdgcn_mfma_f32_16x16x32_bf16(          \
              af[mf], bf[nf], acc[mf][nf], 0, 0, 0);                      \
    }                                                                     \
  } while (0)

  // prologue: tiles 0,1 in flight; wait only for tile 0 (8 of 16)
  G1_ISSUE(0);
  G1_ISSUE(1);
  VMCNT8(); BARX();
  for (int t = 0; t < DD / 64; ++t) {
    const int cur = t & 1;
    G1_COMPUTE(cur);
    if (t == DD / 64 - 1) break;
    BARX();                                  // all waves done reading buf[cur]
    if (t < DD / 64 - 2) { G1_ISSUE(cur); VMCNT8(); }   // tile t+2 into cur; wait t+1
    else VMCNT0();                                       // last: wait final tile
    BARX();                                  // tile t+1 visible to all waves
  }

  // epilogue: nf even = G, nf odd = U (same 16 h-cols)
#pragma unroll
  for (int mf = 0; mf < 4; ++mf)
#pragma unroll
    for (int np = 0; np < 2; ++np) {
      const f32x4 g = acc[mf][2 * np], u = acc[mf][2 * np + 1];
      const int hcol = bx * 64 + (wc * 2 + np) * 16 + lr;
#pragma unroll
      for (int r = 0; r < 4; ++r) {
        const int rl = m0 + wr * 64 + mf * 16 + kc * 4 + r;
        if (rl < ne) {
          const float gg = g[r], uu = u[r];
          const float hv = gg / (1.f + __expf(-gg)) * uu;
          hbuf[(size_t)(off + rl) * HH + hcol] = f2bf(hv);
        }
      }
    }
#undef G1_ISSUE
#undef G1_COMPUTE
}

// ---------------- GEMM2: h(bf16) @ w3t(bf16) * prob -> atomicAdd into out ----------------
// BM=128, BN=128, BK=64; 4 waves (2x2); depth-2 counted-vmcnt pipeline; K=2048.
__global__ __launch_bounds__(256) void gemm2_k(
    const unsigned short* __restrict__ hbuf, const unsigned short* __restrict__ w3t,
    const int* __restrict__ counts, const int* __restrict__ offsets,
    const int* __restrict__ perm, const float* __restrict__ prow,
    const int* __restrict__ wl, float* __restrict__ out) {
  const int bid = blockIdx.x;
  const int band = bid >> 8, r_ = bid & 255;
  const int bx = r_ & 7;
  const int enc = wl[band * 32 + (r_ >> 3)];
  if (enc < 0) return;
  const int e = enc >> 20, m0 = enc & 0xFFFFF;
  const int ne = counts[e], off = offsets[e];
  const int n1 = bx * 128;

  __shared__ unsigned short As[2][128 * 64];
  __shared__ unsigned short Bs[2][128 * 64];

  const int tid = threadIdx.x, lane = tid & 63, wv = tid >> 6;
  const int srow = lane >> 3;
  const int schunk = ((lane & 7) ^ srow) * 8;

  const unsigned short* pA[4];
  const unsigned short* pB[4];
#pragma unroll
  for (int q = 0; q < 4; ++q) {
    const int row = wv * 32 + q * 8 + srow;
    pA[q] = hbuf + (size_t)(off + min(m0 + row, ne - 1)) * HH + schunk;
    pB[q] = w3t + ((size_t)e * DD + n1 + row) * HH + schunk;
  }

  const int wr = wv >> 1, wc = wv & 1;
  const int lr = lane & 15, kc = lane >> 4;

  f32x4 acc[4][4];
#pragma unroll
  for (int a = 0; a < 4; ++a)
#pragma unroll
    for (int b = 0; b < 4; ++b) acc[a][b] = f32x4{0.f, 0.f, 0.f, 0.f};

#define G2_ISSUE(b)                                                       \
  do {                                                                    \
    _Pragma("unroll")                                                     \
    for (int q = 0; q < 4; ++q) {                                         \
      gload16(pA[q], &As[b][(wv * 32 + q * 8) * 64]); pA[q] += 64;        \
      gload16(pB[q], &Bs[b][(wv * 32 + q * 8) * 64]); pB[q] += 64;        \
    }                                                                     \
  } while (0)

#define G2_COMPUTE(b)                                                     \
  do {                                                                    \
    _Pragma("unroll")                                                     \
    for (int kk = 0; kk < 2; ++kk) {                                      \
      bf16x8 af[4], bf[4];                                                \
      _Pragma("unroll")                                                   \
      for (int mf = 0; mf < 4; ++mf)                                      \
        af[mf] = *(const bf16x8*)&As[b][(wr * 64 + mf * 16 + lr) * 64 +   \
                                       ((kk * 4 + kc) ^ (lr & 7)) * 8];   \
      _Pragma("unroll")                                                   \
      for (int nf = 0; nf < 4; ++nf)                                      \
        bf[nf] = *(const bf16x8*)&Bs[b][(wc * 64 + nf * 16 + lr) * 64 +   \
                                       ((kk * 4 + kc) ^ (lr & 7)) * 8];   \
      _Pragma("unroll")                                                   \
      for (int mf = 0; mf < 4; ++mf)                                      \
        _Pragma("unroll")                                                 \
        for (int nf = 0; nf < 4; ++nf)                                    \
          acc[mf][nf] = __builtin_amdgcn_mfma_f32_16x16x32_bf16(          \
              af[mf], bf[nf], acc[mf][nf], 0, 0, 0);                      \
    }                                                                     \
  } while (0)

  G2_ISSUE(0);
  G2_ISSUE(1);
  VMCNT8(); BARX();
  for (int t = 0; t < HH / 64; ++t) {
    const int cur = t & 1;
    G2_COMPUTE(cur);
    if (t == HH / 64 - 1) break;
    BARX();
    if (t < HH / 64 - 2) { G2_ISSUE(cur); VMCNT8(); }
    else VMCNT0();
    BARX();
  }

  // epilogue: out[tok] += prob * acc  (fp32 atomic add, commutative -> deterministic)
#pragma unroll
  for (int mf = 0; mf < 4; ++mf)
#pragma unroll
    for (int r = 0; r < 4; ++r) {
      const int rl = m0 + wr * 64 + mf * 16 + kc * 4 + r;
      if (rl < ne) {
        const int tok = perm[off + rl];
        const float p = prow[off + rl];
        float* op = out + (size_t)tok * DD + n1 + wc * 64 + lr;
#pragma unroll
        for (int nf = 0; nf < 4; ++nf)
          atomicAdd(op + nf * 16, p * acc[mf][nf][r]);
      }
    }
#undef G2_ISSUE
#undef G2_COMPUTE
}

// ---------------- workspace layout ----------------
#define WS_COUNTS 0
#define WS_OFFS 32
#define WS_CURS 64
#define WS_WL 128
#define WS_TOPI (WS_WL + NWL * 4)
#define WS_TOPP (WS_TOPI + TOK * 2 * 4)
#define WS_PERM (WS_TOPP + TOK * 2 * 4)
#define WS_PROW (WS_PERM + RTOT * 4)
#define WS_XB ((WS_PROW + RTOT * 4 + 255) & ~(size_t)255)
#define WS_H (WS_XB + (size_t)TOK * DD * 2)
#define WS_WGU (WS_H + (size_t)RTOT * HH * 2)
#define WS_W3T (WS_WGU + (size_t)NE * 2 * HH * DD * 2)
// end = WS_W3T + NE*DD*HH*2 ~= 136 MB

extern "C" void kernel_launch(void* const* d_in, const int* in_sizes, int n_in,
                              void* d_out, int out_size, void* d_ws, size_t ws_size,
                              hipStream_t stream) {
  const float* x = (const float*)d_in[0];
  const float* gw = (const float*)d_in[1];
  const float* w1 = (const float*)d_in[2];
  const float* w2 = (const float*)d_in[3];
  const float* w3 = (const float*)d_in[4];
  float* out = (float*)d_out;
  char* ws = (char*)d_ws;

  int* counts = (int*)(ws + WS_COUNTS);
  int* offsets = (int*)(ws + WS_OFFS);
  int* cursor = (int*)(ws + WS_CURS);
  int* wl = (int*)(ws + WS_WL);
  int* topi = (int*)(ws + WS_TOPI);
  float* topp = (float*)(ws + WS_TOPP);
  int* perm = (int*)(ws + WS_PERM);
  float* prow = (float*)(ws + WS_PROW);
  unsigned short* Xb = (unsigned short*)(ws + WS_XB);
  unsigned short* hbuf = (unsigned short*)(ws + WS_H);
  unsigned short* wgu = (unsigned short*)(ws + WS_WGU);
  unsigned short* w3t = (unsigned short*)(ws + WS_W3T);

  hipMemsetAsync(ws, 0, 128, stream);
  hipMemsetAsync(out, 0, (size_t)out_size * sizeof(float), stream);
  router_k<<<TOK / 4, 256, 0, stream>>>(x, gw, Xb, topi, topp, counts);
  transpose_k<<<dim3(512, 24), 256, 0, stream>>>(w1, w2, w3, wgu, w3t);
  scan_k<<<1, 64, 0, stream>>>(counts, offsets, cursor, wl);
  scatter_k<<<TOK / 256, 256, 0, stream>>>(topi, topp, cursor, perm, prow);
  // gemm1: 12 bands x 256 blocks (8 wl-slots x 32 B-panels per band); wl padded with -1
  gemm1_k<<<(NWL / 8) * 256, 256, 0, stream>>>(Xb, wgu, counts, offsets, perm, wl, hbuf);
  // gemm2: 3 bands x 256 blocks (32 wl-slots x 8 B-panels per band)
  gemm2_k<<<(NWL / 32) * 256, 256, 0, stream>>>(hbuf, w3t, counts, offsets, perm, prow, wl, out);
}

// Round 10
// 383.085 us; speedup vs baseline: 1.0385x; 1.0253x over previous
//
#include <hip/hip_runtime.h>
#include <hip/hip_bf16.h>

// B=2,S=2048 -> T=4096 tokens, D=1024, H=2048, E=8, top_k=2
#define TOK 4096
#define DD 1024
#define HH 2048
#define NE 8
#define RTOT (TOK * 2)
#define MAXT 40   // max Sum ceil(ne/256) = 8 + 8192/256 = 40

typedef __attribute__((ext_vector_type(8))) short bf16x8;
typedef __attribute__((ext_vector_type(4))) float f32x4;

static __device__ __forceinline__ unsigned short f2bf(float f) {
  union { float f; unsigned int u; } v; v.f = f;
  unsigned int r = v.u + 0x7fffu + ((v.u >> 16) & 1u);
  return (unsigned short)(r >> 16);
}

// async global->LDS, 16B/lane; LDS dest = wave-uniform base + lane*16
static __device__ __forceinline__ void gload16(const unsigned short* g, unsigned short* l) {
  __builtin_amdgcn_global_load_lds(
      (const __attribute__((address_space(1))) unsigned int*)g,
      (__attribute__((address_space(3))) unsigned int*)l, 16, 0, 0);
}

// packed f32x2 -> bf16x2 (RNE), single HW instruction
#define CVT(d, lo, hi) asm("v_cvt_pk_bf16_f32 %0, %1, %2" : "=v"(d) : "v"(lo), "v"(hi))

#define BARX() do { asm volatile("" ::: "memory"); __builtin_amdgcn_s_barrier(); asm volatile("" ::: "memory"); } while (0)
#define VMCNT8() asm volatile("s_waitcnt vmcnt(8)" ::: "memory")
#define VMCNT0() asm volatile("s_waitcnt vmcnt(0)" ::: "memory")

// ---------------- router: fp32 scores, top-2 softmax; also emits Xb (bf16 x) ----------------
__global__ void router_k(const float* __restrict__ x, const float* __restrict__ gw,
                         unsigned short* __restrict__ xb,
                         int* __restrict__ topi, float* __restrict__ topp,
                         int* __restrict__ counts) {
  const int lane = threadIdx.x & 63;
  const int t = blockIdx.x * 4 + (threadIdx.x >> 6);
  const float4* xr = (const float4*)(x + (size_t)t * DD);
  unsigned int* xw = (unsigned int*)(xb + (size_t)t * DD);
  float acc[NE];
#pragma unroll
  for (int e = 0; e < NE; ++e) acc[e] = 0.f;
#pragma unroll
  for (int i = 0; i < 4; ++i) {
    const float4 xv = xr[i * 64 + lane];
    unsigned int p0, p1;
    CVT(p0, xv.x, xv.y);
    CVT(p1, xv.z, xv.w);
    xw[(i * 64 + lane) * 2] = p0;
    xw[(i * 64 + lane) * 2 + 1] = p1;
#pragma unroll
    for (int e = 0; e < NE; ++e) {
      const float4 gv = ((const float4*)(gw + (size_t)e * DD))[i * 64 + lane];
      acc[e] += xv.x * gv.x + xv.y * gv.y + xv.z * gv.z + xv.w * gv.w;
    }
  }
#pragma unroll
  for (int e = 0; e < NE; ++e)
#pragma unroll
    for (int s = 32; s > 0; s >>= 1) acc[e] += __shfl_xor(acc[e], s, 64);
  if (lane == 0) {
    int i0 = 0; float v0 = acc[0];
#pragma unroll
    for (int e = 1; e < NE; ++e) if (acc[e] > v0) { v0 = acc[e]; i0 = e; }
    int i1 = -1; float v1 = -1e30f;
#pragma unroll
    for (int e = 0; e < NE; ++e) if (e != i0 && acc[e] > v1) { v1 = acc[e]; i1 = e; }
    const float ex = __expf(v1 - v0);
    const float inv = 1.f / (1.f + ex);
    topi[t * 2] = i0; topi[t * 2 + 1] = i1;
    topp[t * 2] = inv; topp[t * 2 + 1] = ex * inv;
    atomicAdd(&counts[i0], 1); atomicAdd(&counts[i1], 1);
  }
}

// ---------------- weight transpose+convert ----------------
__global__ __launch_bounds__(256) void transpose_k(
    const float* __restrict__ w1, const float* __restrict__ w2, const float* __restrict__ w3,
    unsigned short* __restrict__ wgu, unsigned short* __restrict__ w3t) {
  const int z = blockIdx.y;
  const int mat = z >> 3, e = z & 7;
  __shared__ unsigned short t[64 * 72];
  const int tid = threadIdx.x;
  const int lane = tid & 63, wv = tid >> 6;

  if (mat < 2) {
    const float* in = (mat ? w2 : w1) + (size_t)e * DD * HH;
    const int tc = blockIdx.x & 31, tr = blockIdx.x >> 5;
    const int c0 = tc * 64, r0 = tr * 64;
#pragma unroll
    for (int p = 0; p < 4; ++p) {
      const int rb = (wv * 4 + p) * 4;
      ushort4 o;
      o.x = f2bf(in[(size_t)(r0 + rb + 0) * HH + c0 + lane]);
      o.y = f2bf(in[(size_t)(r0 + rb + 1) * HH + c0 + lane]);
      o.z = f2bf(in[(size_t)(r0 + rb + 2) * HH + c0 + lane]);
      o.w = f2bf(in[(size_t)(r0 + rb + 3) * HH + c0 + lane]);
      *(ushort4*)&t[lane * 72 + rb] = o;
    }
    __syncthreads();
#pragma unroll
    for (int q = 0; q < 2; ++q) {
      const int idx = q * 256 + tid;
      const int crow = idx >> 3, seg = idx & 7;
      const int j = c0 + crow;
      const int R = ((j >> 4) << 5) + (j & 15) + mat * 16;
      *(uint4*)&wgu[((size_t)e * 2 * HH + R) * DD + r0 + seg * 8] =
          *(const uint4*)&t[crow * 72 + seg * 8];
    }
  } else {
    const float* in = w3 + (size_t)e * HH * DD;
    const int tc = blockIdx.x & 15, tr = blockIdx.x >> 4;
    const int c0 = tc * 64, r0 = tr * 64;
#pragma unroll
    for (int p = 0; p < 4; ++p) {
      const int rb = (wv * 4 + p) * 4;
      ushort4 o;
      o.x = f2bf(in[(size_t)(r0 + rb + 0) * DD + c0 + lane]);
      o.y = f2bf(in[(size_t)(r0 + rb + 1) * DD + c0 + lane]);
      o.z = f2bf(in[(size_t)(r0 + rb + 2) * DD + c0 + lane]);
      o.w = f2bf(in[(size_t)(r0 + rb + 3) * DD + c0 + lane]);
      *(ushort4*)&t[lane * 72 + rb] = o;
    }
    __syncthreads();
#pragma unroll
    for (int q = 0; q < 2; ++q) {
      const int idx = q * 256 + tid;
      const int crow = idx >> 3, seg = idx & 7;
      *(uint4*)&w3t[((size_t)e * DD + c0 + crow) * HH + r0 + seg * 8] =
          *(const uint4*)&t[crow * 72 + seg * 8];
    }
  }
}

// ---------------- scatter (offsets computed inline from counts) ----------------
__global__ void scatter_k(const int* __restrict__ topi, const float* __restrict__ topp,
                          const int* __restrict__ counts, int* __restrict__ cursor,
                          int* __restrict__ perm, float* __restrict__ prow) {
  const int t = blockIdx.x * 256 + threadIdx.x;
  int offs[NE];
  int s = 0;
#pragma unroll
  for (int e = 0; e < NE; ++e) { offs[e] = s; s += counts[e]; }
#pragma unroll
  for (int k = 0; k < 2; ++k) {
    const int e = topi[t * 2 + k];
    const int pos = offs[e] + atomicAdd(&cursor[e], 1);
    perm[pos] = t;
    prow[pos] = topp[t * 2 + k];
  }
}

// ---- inline tile decode: tix -> (expert e, m0, off). returns e==NE if dead. ----
static __device__ __forceinline__ void decode_tile(const int* counts, int tix,
                                                   int& e, int& m0, int& off, int& ne) {
  int t = tix; off = 0;
  for (e = 0; e < NE; ++e) {
    const int c = counts[e];
    const int nt = (c + 255) >> 8;
    if (t < nt) { m0 = t << 8; ne = c; return; }
    t -= nt; off += c;
  }
}

// ---------------- GEMM1: X(gathered bf16) @ wgu(bf16) -> h = silu(g)*u ----------------
// BM=256, BN=256 wgu-rows (128 h-cols), BK=64; 8 waves (2Mx4N, per-wave 128x64).
// 128KB dbuf LDS, counted vmcnt(8) pipeline. FLOP/LDS-byte = 42.7 (vs 32 at 128-tile).
__global__ __launch_bounds__(512, 2) void gemm1_k(
    const unsigned short* __restrict__ Xb, const unsigned short* __restrict__ wgu,
    const int* __restrict__ counts, const int* __restrict__ perm,
    unsigned short* __restrict__ hbuf) {
  const int bx = blockIdx.x & 15;        // B-panel: 256 wgu rows = 128 h-cols
  int e, m0, off, ne;
  decode_tile(counts, blockIdx.x >> 4, e, m0, off, ne);
  if (e == NE) return;

  extern __shared__ __align__(16) unsigned short lds[];
  // As buf b: lds + b*16384 ; Bs buf b: lds + 32768 + b*16384 (shorts)

  const int tid = threadIdx.x, lane = tid & 63, wv = tid >> 6;
  const int srow = lane >> 3;
  const int schunk = ((lane & 7) ^ srow) * 8;

  const unsigned short* pA[4];
  const unsigned short* pB[4];
#pragma unroll
  for (int q = 0; q < 4; ++q) {
    const int row = wv * 32 + q * 8 + srow;
    pA[q] = Xb + (size_t)perm[off + min(m0 + row, ne - 1)] * DD + schunk;
    pB[q] = wgu + ((size_t)e * 2 * HH + bx * 256 + row) * DD + schunk;
  }

  const int wr = wv >> 2, wc = wv & 3;   // 2M x 4N
  const int lr = lane & 15, kc = lane >> 4;

  f32x4 acc[8][4];
#pragma unroll
  for (int a = 0; a < 8; ++a)
#pragma unroll
    for (int b = 0; b < 4; ++b) acc[a][b] = f32x4{0.f, 0.f, 0.f, 0.f};

#define G1_ISSUE(b)                                                       \
  do {                                                                    \
    _Pragma("unroll")                                                     \
    for (int q = 0; q < 4; ++q) {                                         \
      gload16(pA[q], lds + (b) * 16384 + (wv * 32 + q * 8) * 64);         \
      pA[q] += 64;                                                        \
      gload16(pB[q], lds + 32768 + (b) * 16384 + (wv * 32 + q * 8) * 64); \
      pB[q] += 64;                                                        \
    }                                                                     \
  } while (0)

#define G1_COMPUTE(b)                                                     \
  do {                                                                    \
    const unsigned short* Ab = lds + (b) * 16384;                         \
    const unsigned short* Bb = lds + 32768 + (b) * 16384;                 \
    _Pragma("unroll")                                                     \
    for (int kk = 0; kk < 2; ++kk) {                                      \
      bf16x8 af[8], bf[4];                                                \
      _Pragma("unroll")                                                   \
      for (int mf = 0; mf < 8; ++mf)                                      \
        af[mf] = *(const bf16x8*)&Ab[(wr * 128 + mf * 16 + lr) * 64 +     \
                                     ((kk * 4 + kc) ^ (lr & 7)) * 8];     \
      _Pragma("unroll")                                                   \
      for (int nf = 0; nf < 4; ++nf)                                      \
        bf[nf] = *(const bf16x8*)&Bb[(wc * 64 + nf * 16 + lr) * 64 +      \
                                     ((kk * 4 + kc) ^ (lr & 7)) * 8];     \
      _Pragma("unroll")                                                   \
      for (int mf = 0; mf < 8; ++mf)                                      \
        _Pragma("unroll")                                                 \
        for (int nf = 0; nf < 4; ++nf)                                    \
          acc[mf][nf] = __builtin_amdgcn_mfma_f32_16x16x32_bf16(          \
              af[mf], bf[nf], acc[mf][nf], 0, 0, 0);                      \
    }                                                                     \
  } while (0)

  G1_ISSUE(0);
  G1_ISSUE(1);
  VMCNT8(); BARX();
  for (int t = 0; t < DD / 64; ++t) {
    const int cur = t & 1;
    G1_COMPUTE(cur);
    if (t == DD / 64 - 1) break;
    BARX();                                  // all waves done reading buf[cur]
    if (t < DD / 64 - 2) { G1_ISSUE(cur); VMCNT8(); }   // tile t+2 in; wait t+1
    else VMCNT0();
    BARX();                                  // tile t+1 visible
  }

  // epilogue: nf even = G, nf odd = U (same 16 h-cols); pair p = nf>>1
#pragma unroll
  for (int mf = 0; mf < 8; ++mf)
#pragma unroll
    for (int p = 0; p < 2; ++p) {
      const f32x4 g = acc[mf][2 * p], u = acc[mf][2 * p + 1];
      const int hcol = bx * 128 + wc * 32 + p * 16 + lr;
#pragma unroll
      for (int r = 0; r < 4; ++r) {
        const int rl = m0 + wr * 128 + mf * 16 + kc * 4 + r;
        if (rl < ne) {
          const float gg = g[r], uu = u[r];
          const float hv = gg / (1.f + __expf(-gg)) * uu;
          hbuf[(size_t)(off + rl) * HH + hcol] = f2bf(hv);
        }
      }
    }
#undef G1_ISSUE
#undef G1_COMPUTE
}

// ---------------- GEMM2: h(bf16) @ w3t(bf16) * prob -> atomicAdd into out ----------------
// BM=256, BN=256 d-cols, BK=64; 8 waves (4Mx2N, per-wave 64x128); K=2048; 128KB dbuf.
__global__ __launch_bounds__(512, 2) void gemm2_k(
    const unsigned short* __restrict__ hbuf, const unsigned short* __restrict__ w3t,
    const int* __restrict__ counts, const int* __restrict__ perm,
    const float* __restrict__ prow, float* __restrict__ out) {
  const int n1 = (blockIdx.x & 3) * 256;
  int e, m0, off, ne;
  decode_tile(counts, blockIdx.x >> 2, e, m0, off, ne);
  if (e == NE) return;

  extern __shared__ __align__(16) unsigned short lds[];

  const int tid = threadIdx.x, lane = tid & 63, wv = tid >> 6;
  const int srow = lane >> 3;
  const int schunk = ((lane & 7) ^ srow) * 8;

  const unsigned short* pA[4];
  const unsigned short* pB[4];
#pragma unroll
  for (int q = 0; q < 4; ++q) {
    const int row = wv * 32 + q * 8 + srow;
    pA[q] = hbuf + (size_t)(off + min(m0 + row, ne - 1)) * HH + schunk;
    pB[q] = w3t + ((size_t)e * DD + n1 + row) * HH + schunk;
  }

  const int wr = wv >> 1, wc = wv & 1;   // 4M x 2N
  const int lr = lane & 15, kc = lane >> 4;

  f32x4 acc[4][8];
#pragma unroll
  for (int a = 0; a < 4; ++a)
#pragma unroll
    for (int b = 0; b < 8; ++b) acc[a][b] = f32x4{0.f, 0.f, 0.f, 0.f};

#define G2_ISSUE(b)                                                       \
  do {                                                                    \
    _Pragma("unroll")                                                     \
    for (int q = 0; q < 4; ++q) {                                         \
      gload16(pA[q], lds + (b) * 16384 + (wv * 32 + q * 8) * 64);         \
      pA[q] += 64;                                                        \
      gload16(pB[q], lds + 32768 + (b) * 16384 + (wv * 32 + q * 8) * 64); \
      pB[q] += 64;                                                        \
    }                                                                     \
  } while (0)

#define G2_COMPUTE(b)                                                     \
  do {                                                                    \
    const unsigned short* Ab = lds + (b) * 16384;                         \
    const unsigned short* Bb = lds + 32768 + (b) * 16384;                 \
    _Pragma("unroll")                                                     \
    for (int kk = 0; kk < 2; ++kk) {                                      \
      bf16x8 af[4], bf[8];                                                \
      _Pragma("unroll")                                                   \
      for (int mf = 0; mf < 4; ++mf)                                      \
        af[mf] = *(const bf16x8*)&Ab[(wr * 64 + mf * 16 + lr) * 64 +      \
                                     ((kk * 4 + kc) ^ (lr & 7)) * 8];     \
      _Pragma("unroll")                                                   \
      for (int nf = 0; nf < 8; ++nf)                                      \
        bf[nf] = *(const bf16x8*)&Bb[(wc * 128 + nf * 16 + lr) * 64 +     \
                                     ((kk * 4 + kc) ^ (lr & 7)) * 8];     \
      _Pragma("unroll")                                                   \
      for (int mf = 0; mf < 4; ++mf)                                      \
        _Pragma("unroll")                                                 \
        for (int nf = 0; nf < 8; ++nf)                                    \
          acc[mf][nf] = __builtin_amdgcn_mfma_f32_16x16x32_bf16(          \
              af[mf], bf[nf], acc[mf][nf], 0, 0, 0);                      \
    }                                                                     \
  } while (0)

  G2_ISSUE(0);
  G2_ISSUE(1);
  VMCNT8(); BARX();
  for (int t = 0; t < HH / 64; ++t) {
    const int cur = t & 1;
    G2_COMPUTE(cur);
    if (t == HH / 64 - 1) break;
    BARX();
    if (t < HH / 64 - 2) { G2_ISSUE(cur); VMCNT8(); }
    else VMCNT0();
    BARX();
  }

  // epilogue: out[tok] += prob * acc  (fp32 atomic add, commutative)
#pragma unroll
  for (int mf = 0; mf < 4; ++mf)
#pragma unroll
    for (int r = 0; r < 4; ++r) {
      const int rl = m0 + wr * 64 + mf * 16 + kc * 4 + r;
      if (rl < ne) {
        const int tok = perm[off + rl];
        const float p = prow[off + rl];
        float* op = out + (size_t)tok * DD + n1 + wc * 128 + lr;
#pragma unroll
        for (int nf = 0; nf < 8; ++nf)
          atomicAdd(op + nf * 16, p * acc[mf][nf][r]);
      }
    }
#undef G2_ISSUE
#undef G2_COMPUTE
}

// ---------------- workspace layout ----------------
#define WS_COUNTS 0
#define WS_CURS 64
#define WS_TOPI 128
#define WS_TOPP (WS_TOPI + TOK * 2 * 4)
#define WS_PERM (WS_TOPP + TOK * 2 * 4)
#define WS_PROW (WS_PERM + RTOT * 4)
#define WS_XB ((WS_PROW + RTOT * 4 + 255) & ~(size_t)255)
#define WS_H (WS_XB + (size_t)TOK * DD * 2)
#define WS_WGU (WS_H + (size_t)RTOT * HH * 2)
#define WS_W3T (WS_WGU + (size_t)NE * 2 * HH * DD * 2)
// end = WS_W3T + NE*DD*HH*2 ~= 136 MB

extern "C" void kernel_launch(void* const* d_in, const int* in_sizes, int n_in,
                              void* d_out, int out_size, void* d_ws, size_t ws_size,
                              hipStream_t stream) {
  const float* x = (const float*)d_in[0];
  const float* gw = (const float*)d_in[1];
  const float* w1 = (const float*)d_in[2];
  const float* w2 = (const float*)d_in[3];
  const float* w3 = (const float*)d_in[4];
  float* out = (float*)d_out;
  char* ws = (char*)d_ws;

  int* counts = (int*)(ws + WS_COUNTS);
  int* cursor = (int*)(ws + WS_CURS);
  int* topi = (int*)(ws + WS_TOPI);
  float* topp = (float*)(ws + WS_TOPP);
  int* perm = (int*)(ws + WS_PERM);
  float* prow = (float*)(ws + WS_PROW);
  unsigned short* Xb = (unsigned short*)(ws + WS_XB);
  unsigned short* hbuf = (unsigned short*)(ws + WS_H);
  unsigned short* wgu = (unsigned short*)(ws + WS_WGU);
  unsigned short* w3t = (unsigned short*)(ws + WS_W3T);

  hipFuncSetAttribute((const void*)gemm1_k, hipFuncAttributeMaxDynamicSharedMemorySize, 131072);
  hipFuncSetAttribute((const void*)gemm2_k, hipFuncAttributeMaxDynamicSharedMemorySize, 131072);

  hipMemsetAsync(ws, 0, 128, stream);
  hipMemsetAsync(out, 0, (size_t)out_size * sizeof(float), stream);
  router_k<<<TOK / 4, 256, 0, stream>>>(x, gw, Xb, topi, topp, counts);
  transpose_k<<<dim3(512, 24), 256, 0, stream>>>(w1, w2, w3, wgu, w3t);
  scatter_k<<<TOK / 256, 256, 0, stream>>>(topi, topp, counts, cursor, perm, prow);
  // gemm1: MAXT tiles x 16 N-panels; dead tiles exit via decode
  gemm1_k<<<MAXT * 16, 512, 131072, stream>>>(Xb, wgu, counts, perm, hbuf);
  // gemm2: MAXT tiles x 4 N-panels
  gemm2_k<<<MAXT * 4, 512, 131072, stream>>>(hbuf, w3t, counts, perm, prow, out);
}

// Round 11
// 349.762 us; speedup vs baseline: 1.1374x; 1.0953x over previous
//
#include <hip/hip_runtime.h>
#include <hip/hip_bf16.h>

// B=2,S=2048 -> T=4096 tokens, D=1024, H=2048, E=8, top_k=2
#define TOK 4096
#define DD 1024
#define HH 2048
#define NE 8
#define RTOT (TOK * 2)
#define MAXT1 72   // max Sum ceil(ne/128) = 64 + 7 (+1 pad)

typedef __attribute__((ext_vector_type(8))) short bf16x8;
typedef __attribute__((ext_vector_type(4))) float f32x4;

static __device__ __forceinline__ unsigned short f2bf(float f) {
  union { float f; unsigned int u; } v; v.f = f;
  unsigned int r = v.u + 0x7fffu + ((v.u >> 16) & 1u);
  return (unsigned short)(r >> 16);
}

// async global->LDS, 16B/lane; LDS dest = wave-uniform base + lane*16
static __device__ __forceinline__ void gload16(const unsigned short* g, unsigned short* l) {
  __builtin_amdgcn_global_load_lds(
      (const __attribute__((address_space(1))) unsigned int*)g,
      (__attribute__((address_space(3))) unsigned int*)l, 16, 0, 0);
}

// packed f32x2 -> bf16x2 (RNE), single HW instruction
#define CVT(d, lo, hi) asm("v_cvt_pk_bf16_f32 %0, %1, %2" : "=v"(d) : "v"(lo), "v"(hi))

#define BARX() do { asm volatile("" ::: "memory"); __builtin_amdgcn_s_barrier(); asm volatile("" ::: "memory"); } while (0)
#define VMCNT8() asm volatile("s_waitcnt vmcnt(8)" ::: "memory")
#define VMCNT0() asm volatile("s_waitcnt vmcnt(0)" ::: "memory")

// ---------------- fused pre-kernel: router (blocks 0..1023) + transpose (1024..13311) ----
// router: fp32 scores, top-2 softmax, emits Xb; transpose: w1/w2 -> wgu, w3 -> w3t.
__global__ __launch_bounds__(256) void pre_k(
    const float* __restrict__ x, const float* __restrict__ gw,
    unsigned short* __restrict__ xb, int* __restrict__ topi, float* __restrict__ topp,
    int* __restrict__ counts,
    const float* __restrict__ w1, const float* __restrict__ w2, const float* __restrict__ w3,
    unsigned short* __restrict__ wgu, unsigned short* __restrict__ w3t) {
  __shared__ unsigned short tbuf[64 * 72];
  const int tid = threadIdx.x;
  const int lane = tid & 63, wv = tid >> 6;

  if (blockIdx.x < 1024) {
    // ---- router ----
    const int t = blockIdx.x * 4 + wv;
    const float4* xr = (const float4*)(x + (size_t)t * DD);
    unsigned int* xw = (unsigned int*)(xb + (size_t)t * DD);
    float acc[NE];
#pragma unroll
    for (int e = 0; e < NE; ++e) acc[e] = 0.f;
#pragma unroll
    for (int i = 0; i < 4; ++i) {
      const float4 xv = xr[i * 64 + lane];
      unsigned int p0, p1;
      CVT(p0, xv.x, xv.y);
      CVT(p1, xv.z, xv.w);
      xw[(i * 64 + lane) * 2] = p0;
      xw[(i * 64 + lane) * 2 + 1] = p1;
#pragma unroll
      for (int e = 0; e < NE; ++e) {
        const float4 gv = ((const float4*)(gw + (size_t)e * DD))[i * 64 + lane];
        acc[e] += xv.x * gv.x + xv.y * gv.y + xv.z * gv.z + xv.w * gv.w;
      }
    }
#pragma unroll
    for (int e = 0; e < NE; ++e)
#pragma unroll
      for (int s = 32; s > 0; s >>= 1) acc[e] += __shfl_xor(acc[e], s, 64);
    if (lane == 0) {
      int i0 = 0; float v0 = acc[0];
#pragma unroll
      for (int e = 1; e < NE; ++e) if (acc[e] > v0) { v0 = acc[e]; i0 = e; }
      int i1 = -1; float v1 = -1e30f;
#pragma unroll
      for (int e = 0; e < NE; ++e) if (e != i0 && acc[e] > v1) { v1 = acc[e]; i1 = e; }
      const float ex = __expf(v1 - v0);
      const float inv = 1.f / (1.f + ex);
      topi[t * 2] = i0; topi[t * 2 + 1] = i1;
      topp[t * 2] = inv; topp[t * 2 + 1] = ex * inv;
      atomicAdd(&counts[i0], 1); atomicAdd(&counts[i1], 1);
    }
    return;
  }

  // ---- transpose ----
  const int bid = blockIdx.x - 1024;
  const int z = bid >> 9;               // 0..23
  const int xt = bid & 511;
  const int mat = z >> 3, e = z & 7;

  if (mat < 2) {
    const float* in = (mat ? w2 : w1) + (size_t)e * DD * HH;
    const int tc = xt & 31, tr = xt >> 5;
    const int c0 = tc * 64, r0 = tr * 64;
#pragma unroll
    for (int p = 0; p < 4; ++p) {
      const int rb = (wv * 4 + p) * 4;
      ushort4 o;
      o.x = f2bf(in[(size_t)(r0 + rb + 0) * HH + c0 + lane]);
      o.y = f2bf(in[(size_t)(r0 + rb + 1) * HH + c0 + lane]);
      o.z = f2bf(in[(size_t)(r0 + rb + 2) * HH + c0 + lane]);
      o.w = f2bf(in[(size_t)(r0 + rb + 3) * HH + c0 + lane]);
      *(ushort4*)&tbuf[lane * 72 + rb] = o;
    }
    __syncthreads();
#pragma unroll
    for (int q = 0; q < 2; ++q) {
      const int idx = q * 256 + tid;
      const int crow = idx >> 3, seg = idx & 7;
      const int j = c0 + crow;
      const int R = ((j >> 4) << 5) + (j & 15) + mat * 16;
      *(uint4*)&wgu[((size_t)e * 2 * HH + R) * DD + r0 + seg * 8] =
          *(const uint4*)&tbuf[crow * 72 + seg * 8];
    }
  } else {
    const float* in = w3 + (size_t)e * HH * DD;
    const int tc = xt & 15, tr = xt >> 4;
    const int c0 = tc * 64, r0 = tr * 64;
#pragma unroll
    for (int p = 0; p < 4; ++p) {
      const int rb = (wv * 4 + p) * 4;
      ushort4 o;
      o.x = f2bf(in[(size_t)(r0 + rb + 0) * DD + c0 + lane]);
      o.y = f2bf(in[(size_t)(r0 + rb + 1) * DD + c0 + lane]);
      o.z = f2bf(in[(size_t)(r0 + rb + 2) * DD + c0 + lane]);
      o.w = f2bf(in[(size_t)(r0 + rb + 3) * DD + c0 + lane]);
      *(ushort4*)&tbuf[lane * 72 + rb] = o;
    }
    __syncthreads();
#pragma unroll
    for (int q = 0; q < 2; ++q) {
      const int idx = q * 256 + tid;
      const int crow = idx >> 3, seg = idx & 7;
      *(uint4*)&w3t[((size_t)e * DD + c0 + crow) * HH + r0 + seg * 8] =
          *(const uint4*)&tbuf[crow * 72 + seg * 8];
    }
  }
}

// ---------------- deterministic sorted compaction (replaces atomic scatter) ----------------
// Block e emits its expert's tokens in ascending order via ballot prefix-scan.
__global__ __launch_bounds__(256) void compact_k(
    const int* __restrict__ topi, const float* __restrict__ topp,
    const int* __restrict__ counts, int* __restrict__ perm, float* __restrict__ prow) {
  const int e = blockIdx.x;
  const int tid = threadIdx.x, lane = tid & 63, wv = tid >> 6;
  __shared__ int wsum[4];
  __shared__ int cbase;
  if (tid == 0) {
    int b = 0;
    for (int i = 0; i < e; ++i) b += counts[i];
    cbase = b;
  }
  __syncthreads();
  for (int c0 = 0; c0 < TOK; c0 += 256) {
    const int t = c0 + tid;
    const int a = topi[2 * t], b = topi[2 * t + 1];
    const int k = (a == e) ? 0 : ((b == e) ? 1 : -1);
    const unsigned long long bal = __ballot(k >= 0);
    const int rank = __popcll(bal & ((1ull << lane) - 1ull));
    if (lane == 0) wsum[wv] = __popcll(bal);
    __syncthreads();
    int woff = 0;
#pragma unroll
    for (int i = 0; i < 4; ++i) if (i < wv) woff += wsum[i];
    const int ctot = wsum[0] + wsum[1] + wsum[2] + wsum[3];
    if (k >= 0) {
      const int pos = cbase + woff + rank;
      perm[pos] = t;
      prow[pos] = topp[2 * t + k];
    }
    __syncthreads();
    if (tid == 0) cbase += ctot;
    __syncthreads();
  }
}

// ---- inline tile decode (BM=128): tix -> (e, m0, off, ne); false if dead ----
static __device__ __forceinline__ bool decode128(const int* counts, int tix,
                                                 int& e, int& m0, int& off, int& ne) {
  int t = tix; off = 0;
  for (e = 0; e < NE; ++e) {
    const int c = counts[e];
    const int nt = (c + 127) >> 7;
    if (t < nt) { m0 = t << 7; ne = c; return true; }
    t -= nt; off += c;
  }
  return false;
}

// ---------------- GEMM1: X(gathered bf16) @ wgu(bf16) -> h = silu(g)*u ----------------
// BM=128, BN=128 wgu-rows (64 h-cols), BK=64; 4 waves (2x2); depth-2 counted-vmcnt dbuf.
__global__ __launch_bounds__(256) void gemm1_k(
    const unsigned short* __restrict__ Xb, const unsigned short* __restrict__ wgu,
    const int* __restrict__ counts, const int* __restrict__ perm,
    unsigned short* __restrict__ hbuf) {
  const int bx = blockIdx.x & 31;
  int e, m0, off, ne;
  if (!decode128(counts, blockIdx.x >> 5, e, m0, off, ne)) return;

  __shared__ unsigned short As[2][128 * 64];
  __shared__ unsigned short Bs[2][128 * 64];

  const int tid = threadIdx.x, lane = tid & 63, wv = tid >> 6;
  const int srow = lane >> 3;
  const int schunk = ((lane & 7) ^ srow) * 8;

  const unsigned short* pA[4];
  const unsigned short* pB[4];
#pragma unroll
  for (int q = 0; q < 4; ++q) {
    const int row = wv * 32 + q * 8 + srow;
    pA[q] = Xb + (size_t)perm[off + min(m0 + row, ne - 1)] * DD + schunk;
    pB[q] = wgu + ((size_t)e * 2 * HH + bx * 128 + row) * DD + schunk;
  }

  const int wr = wv >> 1, wc = wv & 1;
  const int lr = lane & 15, kc = lane >> 4;

  f32x4 acc[4][4];
#pragma unroll
  for (int a = 0; a < 4; ++a)
#pragma unroll
    for (int b = 0; b < 4; ++b) acc[a][b] = f32x4{0.f, 0.f, 0.f, 0.f};

#define G1_ISSUE(b)                                                       \
  do {                                                                    \
    _Pragma("unroll")                                                     \
    for (int q = 0; q < 4; ++q) {                                         \
      gload16(pA[q], &As[b][(wv * 32 + q * 8) * 64]); pA[q] += 64;        \
      gload16(pB[q], &Bs[b][(wv * 32 + q * 8) * 64]); pB[q] += 64;        \
    }                                                                     \
  } while (0)

#define G1_COMPUTE(b)                                                     \
  do {                                                                    \
    _Pragma("unroll")                                                     \
    for (int kk = 0; kk < 2; ++kk) {                                      \
      bf16x8 af[4], bf[4];                                                \
      _Pragma("unroll")                                                   \
      for (int mf = 0; mf < 4; ++mf)                                      \
        af[mf] = *(const bf16x8*)&As[b][(wr * 64 + mf * 16 + lr) * 64 +   \
                                       ((kk * 4 + kc) ^ (lr & 7)) * 8];   \
      _Pragma("unroll")                                                   \
      for (int nf = 0; nf < 4; ++nf)                                      \
        bf[nf] = *(const bf16x8*)&Bs[b][(wc * 64 + nf * 16 + lr) * 64 +   \
                                       ((kk * 4 + kc) ^ (lr & 7)) * 8];   \
      _Pragma("unroll")                                                   \
      for (int mf = 0; mf < 4; ++mf)                                      \
        _Pragma("unroll")                                                 \
        for (int nf = 0; nf < 4; ++nf)                                    \
          acc[mf][nf] = __builtin_amdgcn_mfma_f32_16x16x32_bf16(          \
              af[mf], bf[nf], acc[mf][nf], 0, 0, 0);                      \
    }                                                                     \
  } while (0)

  G1_ISSUE(0);
  G1_ISSUE(1);
  VMCNT8(); BARX();
  for (int t = 0; t < DD / 64; ++t) {
    const int cur = t & 1;
    G1_COMPUTE(cur);
    if (t == DD / 64 - 1) break;
    BARX();                                  // all waves done reading buf[cur]
    if (t < DD / 64 - 2) { G1_ISSUE(cur); VMCNT8(); }   // tile t+2 in; wait t+1
    else VMCNT0();
    BARX();                                  // tile t+1 visible
  }

  // epilogue: nf even = G, nf odd = U (same 16 h-cols)
#pragma unroll
  for (int mf = 0; mf < 4; ++mf)
#pragma unroll
    for (int np = 0; np < 2; ++np) {
      const f32x4 g = acc[mf][2 * np], u = acc[mf][2 * np + 1];
      const int hcol = bx * 64 + (wc * 2 + np) * 16 + lr;
#pragma unroll
      for (int r = 0; r < 4; ++r) {
        const int rl = m0 + wr * 64 + mf * 16 + kc * 4 + r;
        if (rl < ne) {
          const float gg = g[r], uu = u[r];
          const float hv = gg / (1.f + __expf(-gg)) * uu;
          hbuf[(size_t)(off + rl) * HH + hcol] = f2bf(hv);
        }
      }
    }
#undef G1_ISSUE
#undef G1_COMPUTE
}

// ---------------- GEMM2: h(bf16) @ w3t(bf16) * prob -> atomicAdd into out ----------------
// BM=128, BN=128, BK=64; 4 waves (2x2); depth-2 counted-vmcnt dbuf; K=2048.
__global__ __launch_bounds__(256) void gemm2_k(
    const unsigned short* __restrict__ hbuf, const unsigned short* __restrict__ w3t,
    const int* __restrict__ counts, const int* __restrict__ perm,
    const float* __restrict__ prow, float* __restrict__ out) {
  const int bx = blockIdx.x & 7;
  int e, m0, off, ne;
  if (!decode128(counts, blockIdx.x >> 3, e, m0, off, ne)) return;
  const int n1 = bx * 128;

  __shared__ unsigned short As[2][128 * 64];
  __shared__ unsigned short Bs[2][128 * 64];

  const int tid = threadIdx.x, lane = tid & 63, wv = tid >> 6;
  const int srow = lane >> 3;
  const int schunk = ((lane & 7) ^ srow) * 8;

  const unsigned short* pA[4];
  const unsigned short* pB[4];
#pragma unroll
  for (int q = 0; q < 4; ++q) {
    const int row = wv * 32 + q * 8 + srow;
    pA[q] = hbuf + (size_t)(off + min(m0 + row, ne - 1)) * HH + schunk;
    pB[q] = w3t + ((size_t)e * DD + n1 + row) * HH + schunk;
  }

  const int wr = wv >> 1, wc = wv & 1;
  const int lr = lane & 15, kc = lane >> 4;

  f32x4 acc[4][4];
#pragma unroll
  for (int a = 0; a < 4; ++a)
#pragma unroll
    for (int b = 0; b < 4; ++b) acc[a][b] = f32x4{0.f, 0.f, 0.f, 0.f};

#define G2_ISSUE(b)                                                       \
  do {                                                                    \
    _Pragma("unroll")                                                     \
    for (int q = 0; q < 4; ++q) {                                         \
      gload16(pA[q], &As[b][(wv * 32 + q * 8) * 64]); pA[q] += 64;        \
      gload16(pB[q], &Bs[b][(wv * 32 + q * 8) * 64]); pB[q] += 64;        \
    }                                                                     \
  } while (0)

#define G2_COMPUTE(b)                                                     \
  do {                                                                    \
    _Pragma("unroll")                                                     \
    for (int kk = 0; kk < 2; ++kk) {                                      \
      bf16x8 af[4], bf[4];                                                \
      _Pragma("unroll")                                                   \
      for (int mf = 0; mf < 4; ++mf)                                      \
        af[mf] = *(const bf16x8*)&As[b][(wr * 64 + mf * 16 + lr) * 64 +   \
                                       ((kk * 4 + kc) ^ (lr & 7)) * 8];   \
      _Pragma("unroll")                                                   \
      for (int nf = 0; nf < 4; ++nf)                                      \
        bf[nf] = *(const bf16x8*)&Bs[b][(wc * 64 + nf * 16 + lr) * 64 +   \
                                       ((kk * 4 + kc) ^ (lr & 7)) * 8];   \
      _Pragma("unroll")                                                   \
      for (int mf = 0; mf < 4; ++mf)                                      \
        _Pragma("unroll")                                                 \
        for (int nf = 0; nf < 4; ++nf)                                    \
          acc[mf][nf] = __builtin_amdgcn_mfma_f32_16x16x32_bf16(          \
              af[mf], bf[nf], acc[mf][nf], 0, 0, 0);                      \
    }                                                                     \
  } while (0)

  G2_ISSUE(0);
  G2_ISSUE(1);
  VMCNT8(); BARX();
  for (int t = 0; t < HH / 64; ++t) {
    const int cur = t & 1;
    G2_COMPUTE(cur);
    if (t == HH / 64 - 1) break;
    BARX();
    if (t < HH / 64 - 2) { G2_ISSUE(cur); VMCNT8(); }
    else VMCNT0();
    BARX();
  }

  // epilogue: out[tok] += prob * acc  (fp32 atomic add, commutative -> deterministic)
#pragma unroll
  for (int mf = 0; mf < 4; ++mf)
#pragma unroll
    for (int r = 0; r < 4; ++r) {
      const int rl = m0 + wr * 64 + mf * 16 + kc * 4 + r;
      if (rl < ne) {
        const int tok = perm[off + rl];
        const float p = prow[off + rl];
        float* op = out + (size_t)tok * DD + n1 + wc * 64 + lr;
#pragma unroll
        for (int nf = 0; nf < 4; ++nf)
          atomicAdd(op + nf * 16, p * acc[mf][nf][r]);
      }
    }
#undef G2_ISSUE
#undef G2_COMPUTE
}

// ---------------- workspace layout ----------------
#define WS_COUNTS 0
#define WS_TOPI 128
#define WS_TOPP (WS_TOPI + TOK * 2 * 4)
#define WS_PERM (WS_TOPP + TOK * 2 * 4)
#define WS_PROW (WS_PERM + RTOT * 4)
#define WS_XB ((WS_PROW + RTOT * 4 + 255) & ~(size_t)255)
#define WS_H (WS_XB + (size_t)TOK * DD * 2)
#define WS_WGU (WS_H + (size_t)RTOT * HH * 2)
#define WS_W3T (WS_WGU + (size_t)NE * 2 * HH * DD * 2)
// end = WS_W3T + NE*DD*HH*2 ~= 136 MB

extern "C" void kernel_launch(void* const* d_in, const int* in_sizes, int n_in,
                              void* d_out, int out_size, void* d_ws, size_t ws_size,
                              hipStream_t stream) {
  const float* x = (const float*)d_in[0];
  const float* gw = (const float*)d_in[1];
  const float* w1 = (const float*)d_in[2];
  const float* w2 = (const float*)d_in[3];
  const float* w3 = (const float*)d_in[4];
  float* out = (float*)d_out;
  char* ws = (char*)d_ws;

  int* counts = (int*)(ws + WS_COUNTS);
  int* topi = (int*)(ws + WS_TOPI);
  float* topp = (float*)(ws + WS_TOPP);
  int* perm = (int*)(ws + WS_PERM);
  float* prow = (float*)(ws + WS_PROW);
  unsigned short* Xb = (unsigned short*)(ws + WS_XB);
  unsigned short* hbuf = (unsigned short*)(ws + WS_H);
  unsigned short* wgu = (unsigned short*)(ws + WS_WGU);
  unsigned short* w3t = (unsigned short*)(ws + WS_W3T);

  hipMemsetAsync(ws, 0, 128, stream);
  hipMemsetAsync(out, 0, (size_t)out_size * sizeof(float), stream);
  // fused router (1024 blocks) + weight transpose (12288 blocks)
  pre_k<<<1024 + 12288, 256, 0, stream>>>(x, gw, Xb, topi, topp, counts,
                                          w1, w2, w3, wgu, w3t);
  compact_k<<<NE, 256, 0, stream>>>(topi, topp, counts, perm, prow);
  gemm1_k<<<MAXT1 * 32, 256, 0, stream>>>(Xb, wgu, counts, perm, hbuf);
  gemm2_k<<<MAXT1 * 8, 256, 0, stream>>>(hbuf, w3t, counts, perm, prow, out);
}